// Round 1
// baseline (400.544 us; speedup 1.0000x reference)
//
#include <hip/hip_runtime.h>

// Problem constants (from reference):
//   B=16384, F=100, NCAT=28, CARD=100, C=5, DTOK=128
//   NTOK = NCAT + F = 128 (power of 2!), D = 128, D4 = 32 float4s per row
#define BB    16384
#define FF    100
#define NCATT 28
#define NTOK  128
#define CC    5
#define DD    128
#define DD4   32

__global__ __launch_bounds__(256) void fwe_tok_kernel(
    const float* __restrict__ x_num,    // [B,F]
    const int*   __restrict__ x_cat,    // [B,NCAT]
    const float* __restrict__ fwe_w,    // [F,C]
    const float* __restrict__ fwe_b,    // [F,C]
    const float* __restrict__ prelu_a,  // [1]
    const float* __restrict__ tok_w,    // [F,C,D]
    const float* __restrict__ tok_b,    // [NTOK,D]
    const float* __restrict__ cat_emb,  // [NCAT*CARD, D]
    const int*   __restrict__ cat_off,  // [NCAT]
    float*       __restrict__ out)      // [B,NTOK,D]
{
    const float a = prelu_a[0];
    const long long total = (long long)BB * NTOK * DD4;  // one float4 per work item
    long long stride = (long long)gridDim.x * blockDim.x;
    for (long long g = (long long)blockIdx.x * blockDim.x + threadIdx.x;
         g < total; g += stride) {
        const int d4       = (int)(g & (DD4 - 1));   // float4 index within row
        const long long row = g >> 5;                // (b, t) flattened
        const int t        = (int)(row & (NTOK - 1));
        const int b        = (int)(row >> 7);

        // bias term
        float4 r = *(const float4*)&tok_b[t * DD + d4 * 4];

        if (t < NCATT) {
            // category embedding gather
            const int idx = x_cat[b * NCATT + t] + cat_off[t];
            const float4 e = *(const float4*)&cat_emb[(long long)idx * DD + d4 * 4];
            r.x += e.x; r.y += e.y; r.z += e.z; r.w += e.w;
        } else {
            // numeric feature: scale+bias+PReLU then tiny [C]x[C,D] matmul slice
            const int f = t - NCATT;
            const float x = x_num[b * FF + f];
            #pragma unroll
            for (int c = 0; c < CC; ++c) {
                float h = x * fwe_w[f * CC + c] + fwe_b[f * CC + c];
                h = (h >= 0.0f) ? h : a * h;
                const float4 w = *(const float4*)&tok_w[(f * CC + c) * DD + d4 * 4];
                r.x += h * w.x; r.y += h * w.y; r.z += h * w.z; r.w += h * w.w;
            }
        }

        *(float4*)&out[row * DD + d4 * 4] = r;
    }
}

extern "C" void kernel_launch(void* const* d_in, const int* in_sizes, int n_in,
                              void* d_out, int out_size, void* d_ws, size_t ws_size,
                              hipStream_t stream) {
    const float* x_num   = (const float*)d_in[0];
    const int*   x_cat   = (const int*)  d_in[1];
    const float* fwe_w   = (const float*)d_in[2];
    const float* fwe_b   = (const float*)d_in[3];
    const float* prelu_a = (const float*)d_in[4];
    const float* tok_w   = (const float*)d_in[5];
    const float* tok_b   = (const float*)d_in[6];
    const float* cat_emb = (const float*)d_in[7];
    const int*   cat_off = (const int*)  d_in[8];
    float* out = (float*)d_out;

    // total float4 work items = B*NTOK*D/4 = 67,108,864
    const int block = 256;
    const int grid  = 16384;  // grid-stride, 16 iters/thread; 256 CUs well saturated
    fwe_tok_kernel<<<grid, block, 0, stream>>>(
        x_num, x_cat, fwe_w, fwe_b, prelu_a, tok_w, tok_b, cat_emb, cat_off, out);
}

// Round 2
// 202.790 us; speedup vs baseline: 1.9752x; 1.9752x over previous
//
#include <hip/hip_runtime.h>

// Problem constants (from reference):
//   B=16384, F=100, NCAT=28, CARD=100, C=5, DTOK=128
//   NTOK = NCAT + F = 128, D = 128, D4 = 32 float4s per row
#define BB    16384
#define FF    100
#define NCATT 28
#define NTOK  128
#define CC    5
#define DD    128
#define DD4   32
#define NB    64   // b-rows per block
// grid = NTOK * (BB/NB) = 128 * 256 = 32768 blocks

__global__ __launch_bounds__(256) void fwe_tok_kernel(
    const float* __restrict__ x_num,    // [B,F]
    const int*   __restrict__ x_cat,    // [B,NCAT]
    const float* __restrict__ fwe_w,    // [F,C]
    const float* __restrict__ fwe_b,    // [F,C]
    const float* __restrict__ prelu_a,  // [1]
    const float* __restrict__ tok_w,    // [F,C,D]
    const float* __restrict__ tok_b,    // [NTOK,D]
    const float* __restrict__ cat_emb,  // [NCAT*CARD, D]
    const int*   __restrict__ cat_off,  // [NCAT]
    float*       __restrict__ out)      // [B,NTOK,D]
{
    const int t     = blockIdx.x & (NTOK - 1);        // token index (block-uniform)
    const int bBase = (blockIdx.x >> 7) * NB;         // batch chunk base
    const int d4    = threadIdx.x & 31;               // float4 index within D
    const int bi    = threadIdx.x >> 5;               // 0..7 batch sub-lane

    // token bias slice: reused for all NB rows
    const float4 tb = *(const float4*)&tok_b[t * DD + d4 * 4];

    if (t < NCATT) {
        // ---- category path: gather + bias ----
        const int off = cat_off[t];
        #pragma unroll
        for (int j = 0; j < NB / 8; ++j) {
            const int b   = bBase + bi * (NB / 8) + j;
            const int idx = x_cat[b * NCATT + t] + off;
            const float4 e = *(const float4*)&cat_emb[(long long)idx * DD + d4 * 4];
            float4 r;
            r.x = tb.x + e.x; r.y = tb.y + e.y; r.z = tb.z + e.z; r.w = tb.w + e.w;
            *(float4*)&out[((long long)b * NTOK + t) * DD + d4 * 4] = r;
        }
    } else {
        // ---- numeric path: scale+bias+PReLU then [C]x[C,D] matmul slice ----
        const int f = t - NCATT;
        const float a = prelu_a[0];

        // per-feature scalars (block-uniform) and weight slices (per-d4),
        // hoisted out of the b-loop: 5 float4 = 20 VGPRs, loaded once.
        float wf[CC], bf[CC];
        float4 w[CC];
        #pragma unroll
        for (int c = 0; c < CC; ++c) {
            wf[c] = fwe_w[f * CC + c];
            bf[c] = fwe_b[f * CC + c];
            w[c]  = *(const float4*)&tok_w[(f * CC + c) * DD + d4 * 4];
        }

        #pragma unroll
        for (int j = 0; j < NB / 8; ++j) {
            const int b = bBase + bi * (NB / 8) + j;
            const float x = x_num[b * FF + f];
            float4 r = tb;
            #pragma unroll
            for (int c = 0; c < CC; ++c) {
                float h = fmaf(x, wf[c], bf[c]);
                h = (h >= 0.0f) ? h : a * h;
                r.x = fmaf(h, w[c].x, r.x);
                r.y = fmaf(h, w[c].y, r.y);
                r.z = fmaf(h, w[c].z, r.z);
                r.w = fmaf(h, w[c].w, r.w);
            }
            *(float4*)&out[((long long)b * NTOK + t) * DD + d4 * 4] = r;
        }
    }
}

extern "C" void kernel_launch(void* const* d_in, const int* in_sizes, int n_in,
                              void* d_out, int out_size, void* d_ws, size_t ws_size,
                              hipStream_t stream) {
    const float* x_num   = (const float*)d_in[0];
    const int*   x_cat   = (const int*)  d_in[1];
    const float* fwe_w   = (const float*)d_in[2];
    const float* fwe_b   = (const float*)d_in[3];
    const float* prelu_a = (const float*)d_in[4];
    const float* tok_w   = (const float*)d_in[5];
    const float* tok_b   = (const float*)d_in[6];
    const float* cat_emb = (const float*)d_in[7];
    const int*   cat_off = (const int*)  d_in[8];
    float* out = (float*)d_out;

    const int block = 256;
    const int grid  = NTOK * (BB / NB);   // 32768
    fwe_tok_kernel<<<grid, block, 0, stream>>>(
        x_num, x_cat, fwe_w, fwe_b, prelu_a, tok_w, tok_b, cat_emb, cat_off, out);
}

// Round 3
// 197.155 us; speedup vs baseline: 2.0316x; 1.0286x over previous
//
#include <hip/hip_runtime.h>

// Problem constants (from reference):
//   B=16384, F=100, NCAT=28, CARD=100, C=5, DTOK=128
//   NTOK = NCAT + F = 128, D = 128, D4 = 32 float4s per row
#define BB    16384
#define FF    100
#define NCATT 28
#define NTOK  128
#define CC    5
#define DD    128
#define DD4   32
#define NB    64   // b-rows per block
// grid = NTOK * (BB/NB) = 128 * 256 = 32768 blocks

typedef float f32x4 __attribute__((ext_vector_type(4)));

__global__ __launch_bounds__(256) void fwe_tok_kernel(
    const float* __restrict__ x_num,    // [B,F]
    const int*   __restrict__ x_cat,    // [B,NCAT]
    const float* __restrict__ fwe_w,    // [F,C]
    const float* __restrict__ fwe_b,    // [F,C]
    const float* __restrict__ prelu_a,  // [1]
    const float* __restrict__ tok_w,    // [F,C,D]
    const float* __restrict__ tok_b,    // [NTOK,D]
    const float* __restrict__ cat_emb,  // [NCAT*CARD, D]
    const int*   __restrict__ cat_off,  // [NCAT]
    float*       __restrict__ out)      // [B,NTOK,D]
{
    const int t     = blockIdx.x & (NTOK - 1);        // token index (block-uniform)
    const int bBase = (blockIdx.x >> 7) * NB;         // batch chunk base
    const int d4    = threadIdx.x & 31;               // float4 index within D
    const int bi    = threadIdx.x >> 5;               // 0..7 batch sub-lane

    // token bias slice: reused for all NB rows
    const f32x4 tb = *(const f32x4*)&tok_b[t * DD + d4 * 4];

    if (t < NCATT) {
        // ---- category path: gather + bias ----
        const int off = cat_off[t];
        #pragma unroll
        for (int j = 0; j < NB / 8; ++j) {
            const int b   = bBase + bi * (NB / 8) + j;
            const int idx = x_cat[b * NCATT + t] + off;
            const f32x4 e = *(const f32x4*)&cat_emb[(long long)idx * DD + d4 * 4];
            f32x4 r = tb + e;
            __builtin_nontemporal_store(r, (f32x4*)&out[((long long)b * NTOK + t) * DD + d4 * 4]);
        }
    } else {
        // ---- numeric path: scale+bias+PReLU then [C]x[C,D] matmul slice ----
        const int f = t - NCATT;
        const float a = prelu_a[0];

        // per-feature scalars (block-uniform) and weight slices (per-d4),
        // hoisted out of the b-loop: 5 float4 = 20 VGPRs, loaded once.
        float wf[CC], bf[CC];
        f32x4 w[CC];
        #pragma unroll
        for (int c = 0; c < CC; ++c) {
            wf[c] = fwe_w[f * CC + c];
            bf[c] = fwe_b[f * CC + c];
            w[c]  = *(const f32x4*)&tok_w[(f * CC + c) * DD + d4 * 4];
        }

        #pragma unroll
        for (int j = 0; j < NB / 8; ++j) {
            const int b = bBase + bi * (NB / 8) + j;
            const float x = x_num[b * FF + f];
            f32x4 r = tb;
            #pragma unroll
            for (int c = 0; c < CC; ++c) {
                float h = fmaf(x, wf[c], bf[c]);
                h = (h >= 0.0f) ? h : a * h;
                r += h * w[c];
            }
            __builtin_nontemporal_store(r, (f32x4*)&out[((long long)b * NTOK + t) * DD + d4 * 4]);
        }
    }
}

extern "C" void kernel_launch(void* const* d_in, const int* in_sizes, int n_in,
                              void* d_out, int out_size, void* d_ws, size_t ws_size,
                              hipStream_t stream) {
    const float* x_num   = (const float*)d_in[0];
    const int*   x_cat   = (const int*)  d_in[1];
    const float* fwe_w   = (const float*)d_in[2];
    const float* fwe_b   = (const float*)d_in[3];
    const float* prelu_a = (const float*)d_in[4];
    const float* tok_w   = (const float*)d_in[5];
    const float* tok_b   = (const float*)d_in[6];
    const float* cat_emb = (const float*)d_in[7];
    const int*   cat_off = (const int*)  d_in[8];
    float* out = (float*)d_out;

    const int block = 256;
    const int grid  = NTOK * (BB / NB);   // 32768
    fwe_tok_kernel<<<grid, block, 0, stream>>>(
        x_num, x_cat, fwe_w, fwe_b, prelu_a, tok_w, tok_b, cat_emb, cat_off, out);
}

// Round 4
// 189.636 us; speedup vs baseline: 2.1122x; 1.0397x over previous
//
#include <hip/hip_runtime.h>

// Problem constants: B=16384, F=100, NCAT=28, CARD=100, C=5, DTOK=128
// NTOK = 128, D = 128. Output [B,128,128] f32 = 1.074 GB (write-bound).
#define BB    16384
#define FF    100
#define NCATT 28
#define NTOK  128
#define CC    5
#define DD    128
#define NB    64   // b-rows per block
// Block geometry: 256 thr = 32 d4 x 2 tp (token-in-pair) x 4 bi.
// One wave (64 lanes) = d4 0..31 x tp 0..1 for ONE b -> contiguous 1 KB store.
// Grid: 64 t-pairs x 256 bchunks = 16384, bchunk-major, XCD-swizzled so each
// XCD owns 32 consecutive bchunks (contiguous 128 MB write stream, L2-resident
// x_num slab).

typedef float f32x4 __attribute__((ext_vector_type(4)));

__global__ __launch_bounds__(256) void fwe_tok_kernel(
    const float* __restrict__ x_num,    // [B,F]
    const int*   __restrict__ x_cat,    // [B,NCAT]
    const float* __restrict__ fwe_w,    // [F,C]
    const float* __restrict__ fwe_b,    // [F,C]
    const float* __restrict__ prelu_a,  // [1]
    const float* __restrict__ tok_w,    // [F,C,D]
    const float* __restrict__ tok_b,    // [NTOK,D]
    const float* __restrict__ cat_emb,  // [NCAT*CARD, D]
    const int*   __restrict__ cat_off,  // [NCAT]
    float*       __restrict__ out)      // [B,NTOK,D]
{
    // Bijective XCD swizzle (grid % 8 == 0): XCD j gets logical blocks
    // [j*cpx, (j+1)*cpx) -- consecutive bchunks stay on one XCD.
    const int cpx     = gridDim.x >> 3;                       // 2048
    const int logical = (blockIdx.x & 7) * cpx + (blockIdx.x >> 3);

    const int tpair = logical & 63;          // 0..63 -> tokens (2*tpair, 2*tpair+1)
    const int bBase = (logical >> 6) * NB;   // bchunk-major

    const int d4 = threadIdx.x & 31;         // float4 index within D
    const int tp = (threadIdx.x >> 5) & 1;   // token within pair
    const int bi = threadIdx.x >> 6;         // 0..3 batch sub-group

    const int t = tpair * 2 + tp;

    const f32x4 tb = *(const f32x4*)&tok_b[t * DD + d4 * 4];

    if (t < NCATT) {   // tpair <= 13: both tokens categorical (block-uniform)
        const int off = cat_off[t];
        #pragma unroll
        for (int j = 0; j < NB / 4; ++j) {
            const int b   = bBase + bi * (NB / 4) + j;
            const int idx = x_cat[b * NCATT + t] + off;
            const f32x4 e = *(const f32x4*)&cat_emb[(long long)idx * DD + d4 * 4];
            f32x4 r = tb + e;
            __builtin_nontemporal_store(r, (f32x4*)&out[((long long)b * NTOK + t) * DD + d4 * 4]);
        }
    } else {           // both tokens numeric (NCAT=28 even -> block-uniform)
        const int f = t - NCATT;
        const float a = prelu_a[0];

        // Per-feature scalars + weight slices hoisted: 5 float4 = 20 VGPRs.
        float wf[CC], bf[CC];
        f32x4 w[CC];
        #pragma unroll
        for (int c = 0; c < CC; ++c) {
            wf[c] = fwe_w[f * CC + c];
            bf[c] = fwe_b[f * CC + c];
            w[c]  = *(const f32x4*)&tok_w[(f * CC + c) * DD + d4 * 4];
        }

        #pragma unroll
        for (int j = 0; j < NB / 4; ++j) {
            const int b = bBase + bi * (NB / 4) + j;
            const float x = x_num[b * FF + f];
            f32x4 r = tb;
            #pragma unroll
            for (int c = 0; c < CC; ++c) {
                float h = fmaf(x, wf[c], bf[c]);
                h = (h >= 0.0f) ? h : a * h;
                r += h * w[c];
            }
            __builtin_nontemporal_store(r, (f32x4*)&out[((long long)b * NTOK + t) * DD + d4 * 4]);
        }
    }
}

extern "C" void kernel_launch(void* const* d_in, const int* in_sizes, int n_in,
                              void* d_out, int out_size, void* d_ws, size_t ws_size,
                              hipStream_t stream) {
    const float* x_num   = (const float*)d_in[0];
    const int*   x_cat   = (const int*)  d_in[1];
    const float* fwe_w   = (const float*)d_in[2];
    const float* fwe_b   = (const float*)d_in[3];
    const float* prelu_a = (const float*)d_in[4];
    const float* tok_w   = (const float*)d_in[5];
    const float* tok_b   = (const float*)d_in[6];
    const float* cat_emb = (const float*)d_in[7];
    const int*   cat_off = (const int*)  d_in[8];
    float* out = (float*)d_out;

    const int block = 256;
    const int grid  = 64 * (BB / NB);   // 64 t-pairs x 256 bchunks = 16384
    fwe_tok_kernel<<<grid, block, 0, stream>>>(
        x_num, x_cat, fwe_w, fwe_b, prelu_a, tok_w, tok_b, cat_emb, cat_off, out);
}